// Round 3
// baseline (2529.820 us; speedup 1.0000x reference)
//
#include <hip/hip_runtime.h>
#include <hip/hip_bf16.h>
#include <math.h>

#define B_    8
#define R_    64
#define C_    16
#define D_    128
#define NPAIR 2016
#define CD    2048
#define LSTR  132   // padded LDS row stride in floats (2-way bank aliasing only -> free)

#define NEG_BIG (-1e30f)

__device__ __forceinline__ float sigmoid_safe(float x){
    x = fminf(fmaxf(x, -30.f), 30.f);   // avoid inf under fast-math
    return 1.f / (1.f + __expf(-x));
}

// X (16 x 128, fp32 in LDS w/ stride LSTR) @ W (128x128 fp32, row-major) + bias.
// Thread t owns output (c = t&15, j = (t>>4)*8 + jj), jj in [0,8).
__device__ __forceinline__ void mm16(const float* __restrict__ shX,
                                     const float* __restrict__ W,
                                     const float* __restrict__ bias,
                                     int t, float acc[8])
{
    const int c = t & 15, jg = t >> 4;
    const float4 b0 = *reinterpret_cast<const float4*>(bias + jg*8);
    const float4 b1 = *reinterpret_cast<const float4*>(bias + jg*8 + 4);
    acc[0]=b0.x; acc[1]=b0.y; acc[2]=b0.z; acc[3]=b0.w;
    acc[4]=b1.x; acc[5]=b1.y; acc[6]=b1.z; acc[7]=b1.w;
    const float* Wp = W + jg*8;
    const float* xrow = shX + c*LSTR;
    #pragma unroll 4
    for (int k = 0; k < 128; ++k){
        const float xv = xrow[k];
        const float4 w0 = *reinterpret_cast<const float4*>(Wp + k*128);
        const float4 w1 = *reinterpret_cast<const float4*>(Wp + k*128 + 4);
        acc[0] = fmaf(xv, w0.x, acc[0]);
        acc[1] = fmaf(xv, w0.y, acc[1]);
        acc[2] = fmaf(xv, w0.z, acc[2]);
        acc[3] = fmaf(xv, w0.w, acc[3]);
        acc[4] = fmaf(xv, w1.x, acc[4]);
        acc[5] = fmaf(xv, w1.y, acc[5]);
        acc[6] = fmaf(xv, w1.z, acc[6]);
        acc[7] = fmaf(xv, w1.w, acc[7]);
    }
}

// K = batch_input @ kW + kb, stored fp32 in workspace. One block per (b,r).
__global__ __launch_bounds__(256) void k_prep(const float* __restrict__ x,
        const float* __restrict__ kW, const float* __restrict__ kb,
        float* __restrict__ Kmat)
{
    __shared__ float shX[C_*LSTR];
    const int t = threadIdx.x;
    const long base = (long)blockIdx.x * CD;
    const float* xp = x + base;
    {
        const int pos = 8*t, cc0 = pos >> 7, d0 = pos & 127;
        const float4 v0 = *reinterpret_cast<const float4*>(xp + pos);
        const float4 v1 = *reinterpret_cast<const float4*>(xp + pos + 4);
        float* dst = &shX[cc0*LSTR + d0];
        *reinterpret_cast<float4*>(dst)     = v0;
        *reinterpret_cast<float4*>(dst + 4) = v1;
    }
    __syncthreads();
    float acc[8];
    mm16(shX, kW, kb, t, acc);
    const int c = t & 15, jg = t >> 4;
    float* o = Kmat + base + c*128 + jg*8;
    #pragma unroll
    for (int jj = 0; jj < 8; ++jj) o[jj] = acc[jj];
}

// One block per (pair p = blockIdx.x, batch b = blockIdx.y). Fully fused pipeline.
__global__ __launch_bounds__(256) void k_pair(
    const float* __restrict__ x, const float* __restrict__ seq_mask,
    const int* __restrict__ row, const int* __restrict__ col,
    const float* __restrict__ hW, const float* __restrict__ hb,
    const float* __restrict__ gW, const float* __restrict__ gb,
    const float* __restrict__ qW, const float* __restrict__ qb,
    const float* __restrict__ s1W, const float* __restrict__ s1b,
    const float* __restrict__ s2W, const float* __restrict__ s2b,
    const float* __restrict__ Kmat, float* __restrict__ out)
{
    __shared__ float shA[C_*LSTR];   // diff -> q
    __shared__ float shB[C_*LSTR];   // xj   -> x_glob
    __shared__ float shC[C_*LSTR];   // x (gated), updated in place
    __shared__ float shAlpha[R_];
    __shared__ float shRed[64];

    const int t = threadIdx.x;
    const int p = blockIdx.x, b = blockIdx.y;
    const int ri = row[p], ci = col[p];
    const float* xb = x + (long)b * R_ * CD;
    const float* xi = xb + (long)ri * CD;
    const float* xj = xb + (long)ci * CD;

    // stage xi-xj (A) and xj (B)
    {
        const int pos = 8*t, cc0 = pos >> 7, d0 = pos & 127;
        const float4 i0 = *reinterpret_cast<const float4*>(xi + pos);
        const float4 i1 = *reinterpret_cast<const float4*>(xi + pos + 4);
        const float4 j0 = *reinterpret_cast<const float4*>(xj + pos);
        const float4 j1 = *reinterpret_cast<const float4*>(xj + pos + 4);
        float* a = &shA[cc0*LSTR + d0];
        float* bb = &shB[cc0*LSTR + d0];
        a[0]=i0.x-j0.x; a[1]=i0.y-j0.y; a[2]=i0.z-j0.z; a[3]=i0.w-j0.w;
        a[4]=i1.x-j1.x; a[5]=i1.y-j1.y; a[6]=i1.z-j1.z; a[7]=i1.w-j1.w;
        bb[0]=j0.x; bb[1]=j0.y; bb[2]=j0.z; bb[3]=j0.w;
        bb[4]=j1.x; bb[5]=j1.y; bb[6]=j1.z; bb[7]=j1.w;
    }
    __syncthreads();

    const int c = t & 15, jg = t >> 4;
    const int abase = c*LSTR + jg*8;
    float acc[8];

    // h = diff @ hW + hb; z = sigmoid(h); x = xj + z*diff -> shC
    mm16(shA, hW, hb, t, acc);
    #pragma unroll
    for (int jj = 0; jj < 8; ++jj){
        const float z = sigmoid_safe(acc[jj]);
        shC[abase+jj] = shB[abase+jj] + z * shA[abase+jj];
    }
    __syncthreads();

    // q = x @ qW + qb -> shA (diff dead)
    mm16(shC, qW, qb, t, acc);
    #pragma unroll
    for (int jj = 0; jj < 8; ++jj) shA[abase+jj] = acc[jj];
    __syncthreads();

    // alpha[r] = scale * <q, K[b,r]>  -- wave handles 16 r's, lane covers d-pairs
    {
        const int wave = t >> 6, lane = t & 63;
        const float* Kb = Kmat + (long)b * R_ * CD;
        for (int rr = 0; rr < 16; ++rr){
            const int r = wave*16 + rr;
            const float* Kr = Kb + r*CD;
            float part = 0.f;
            #pragma unroll
            for (int cc = 0; cc < 16; ++cc){
                const float2 kv = *reinterpret_cast<const float2*>(Kr + cc*128 + 2*lane);
                const float2 qv = *reinterpret_cast<const float2*>(&shA[cc*LSTR + 2*lane]);
                part = fmaf(qv.x, kv.x, part);
                part = fmaf(qv.y, kv.y, part);
            }
            #pragma unroll
            for (int s = 1; s < 64; s <<= 1) part += __shfl_xor(part, s);
            if (lane == 0) shAlpha[r] = part * 0.022097086912079608f;  // 1/sqrt(2048)
        }
    }
    __syncthreads();

    // mask + softmax over r (wave 0) -- finite NEG_BIG, no inf under fast-math
    if (t < 64){
        float v = shAlpha[t];
        const bool masked = (t == ri || t == ci);
        if (masked) v = NEG_BIG;
        float m = v;
        #pragma unroll
        for (int s = 1; s < 64; s <<= 1) m = fmaxf(m, __shfl_xor(m, s));
        float arg = fmaxf(v - m, -80.f);
        const float e = masked ? 0.f : __expf(arg);
        float ssum = e;
        #pragma unroll
        for (int s = 1; s < 64; s <<= 1) ssum += __shfl_xor(ssum, s);
        shAlpha[t] = e / ssum;
    }
    __syncthreads();

    // x_glob = sum_r alpha[r] * input[b,r] -> shB (xj dead)
    {
        float xg[8] = {0,0,0,0,0,0,0,0};
        const float* xrow = xb + 8*t;
        for (int r = 0; r < 64; ++r){
            const float a = shAlpha[r];
            const float4 v0 = *reinterpret_cast<const float4*>(xrow + r*CD);
            const float4 v1 = *reinterpret_cast<const float4*>(xrow + r*CD + 4);
            xg[0] = fmaf(a, v0.x, xg[0]);
            xg[1] = fmaf(a, v0.y, xg[1]);
            xg[2] = fmaf(a, v0.z, xg[2]);
            xg[3] = fmaf(a, v0.w, xg[3]);
            xg[4] = fmaf(a, v1.x, xg[4]);
            xg[5] = fmaf(a, v1.y, xg[5]);
            xg[6] = fmaf(a, v1.z, xg[6]);
            xg[7] = fmaf(a, v1.w, xg[7]);
        }
        const int pos = 8*t, c2 = pos >> 7, d0 = pos & 127;
        float* dst = &shB[c2*LSTR + d0];
        #pragma unroll
        for (int jj = 0; jj < 8; ++jj) dst[jj] = xg[jj];
    }
    __syncthreads();

    // g = x_glob @ gW + gb; w = sigmoid; x = (1-w)*x + w*x_glob  (in-place shC)
    mm16(shB, gW, gb, t, acc);
    #pragma unroll
    for (int jj = 0; jj < 8; ++jj){
        const float w = sigmoid_safe(acc[jj]);
        shC[abase+jj] = (1.f - w)*shC[abase+jj] + w*shB[abase+jj];
    }
    __syncthreads();

    // s = gelu_exact(x @ s1W + s1b) @ s2W + s2b; out[b,p] = sum_c s[c]*mask[b,c]
    mm16(shC, s1W, s1b, t, acc);
    {
        const float4 s0 = *reinterpret_cast<const float4*>(s2W + jg*8);
        const float4 s1 = *reinterpret_cast<const float4*>(s2W + jg*8 + 4);
        const float s2f[8] = {s0.x, s0.y, s0.z, s0.w, s1.x, s1.y, s1.z, s1.w};
        float part = 0.f;
        #pragma unroll
        for (int jj = 0; jj < 8; ++jj){
            const float tv = acc[jj];
            const float gl = 0.5f * tv * (1.f + erff(tv * 0.70710678118654752f));
            part = fmaf(gl, s2f[jj], part);
        }
        part += __shfl_xor(part, 16);   // fold 4 jg-groups within wave -> lanes<16 hold row sums
        part += __shfl_xor(part, 32);
        const int wave = t >> 6, lane = t & 63;
        if (lane < 16) shRed[wave*16 + lane] = part;
    }
    __syncthreads();
    if (t == 0){
        const float s2bf = s2b[0];
        float o = 0.f;
        #pragma unroll
        for (int cc = 0; cc < 16; ++cc){
            const float s = shRed[cc] + shRed[16+cc] + shRed[32+cc] + shRed[48+cc] + s2bf;
            o += s * seq_mask[b*C_ + cc];
        }
        out[b*NPAIR + p] = o;
    }
}

extern "C" void kernel_launch(void* const* d_in, const int* in_sizes, int n_in,
                              void* d_out, int out_size, void* d_ws, size_t ws_size,
                              hipStream_t stream)
{
    const float* x    = (const float*)d_in[0];
    const float* mask = (const float*)d_in[1];
    const int*   row  = (const int*)d_in[2];
    const int*   col  = (const int*)d_in[3];
    const float* hW  = (const float*)d_in[4];  const float* hb  = (const float*)d_in[5];
    const float* gW  = (const float*)d_in[6];  const float* gb  = (const float*)d_in[7];
    const float* qW  = (const float*)d_in[8];  const float* qb  = (const float*)d_in[9];
    const float* kW  = (const float*)d_in[10]; const float* kb  = (const float*)d_in[11];
    const float* s1W = (const float*)d_in[12]; const float* s1b = (const float*)d_in[13];
    const float* s2W = (const float*)d_in[14]; const float* s2b = (const float*)d_in[15];

    float* Kmat = (float*)d_ws;   // B*R*C*D fp32 = 4 MB

    k_prep<<<B_*R_, 256, 0, stream>>>(x, kW, kb, Kmat);
    k_pair<<<dim3(NPAIR, B_), 256, 0, stream>>>(x, mask, row, col,
                                                hW, hb, gW, gb, qW, qb,
                                                s1W, s1b, s2W, s2b,
                                                Kmat, (float*)d_out);
}

// Round 4
// 753.087 us; speedup vs baseline: 3.3593x; 3.3593x over previous
//
#include <hip/hip_runtime.h>
#include <hip/hip_bf16.h>
#include <math.h>

#define B_    8
#define R_    64
#define C_    16
#define D_    128
#define NPAIR 2016
#define CD    2048
#define PG    4
#define LSTR  132
#define NEG_BIG (-1e30f)
#define SCALE 0.022097086912079608f   // 1/sqrt(2048)

typedef __attribute__((ext_vector_type(8))) short short8;
typedef __attribute__((ext_vector_type(4))) float float4v;

// ---- workspace layout (ushort element offsets) ----
#define WTHI 0u
#define WTLO 65536u
#define KHI  131072u
#define KLO  1179648u
#define XTHI 2228224u
#define XTLO 3276800u
// total 4325376 ushorts = 8.65 MB

__device__ __forceinline__ void split_bf(float v, unsigned short* hi, unsigned short* lo){
    __hip_bfloat16 h = __float2bfloat16(v);
    float hf = __bfloat162float(h);
    __hip_bfloat16 l = __float2bfloat16(v - hf);
    *hi = *reinterpret_cast<unsigned short*>(&h);
    *lo = *reinterpret_cast<unsigned short*>(&l);
}
__device__ __forceinline__ float join_bf(unsigned short hi, unsigned short lo){
    union { unsigned int i; float f; } a, b;
    a.i = ((unsigned int)hi) << 16; b.i = ((unsigned int)lo) << 16;
    return a.f + b.f;
}
__device__ __forceinline__ float sigmoid_safe(float x){
    x = fminf(fmaxf(x, -30.f), 30.f);
    return 1.f / (1.f + __expf(-x));
}
__device__ __forceinline__ int sel4(int i, int a, int b, int c, int d){
    return i==0 ? a : (i==1 ? b : (i==2 ? c : d));
}

// ---------- prep: transposed split weights WT[mat][n][k] ----------
__global__ __launch_bounds__(256) void prep_wt(const float* __restrict__ hW,
        const float* __restrict__ qW, const float* __restrict__ gW,
        const float* __restrict__ s1W, unsigned short* __restrict__ ws)
{
    const int gid = blockIdx.x*256 + threadIdx.x;   // < 65536
    const int mat = gid >> 14, rem = gid & 16383, n = rem >> 7, k = rem & 127;
    const float* W = (mat==0) ? hW : (mat==1) ? qW : (mat==2) ? gW : s1W;
    const float v = W[k*128 + n];
    split_bf(v, ws + WTHI + gid, ws + WTLO + gid);
}

// ---------- prep: XT[b][cd][r] split ----------
__global__ __launch_bounds__(256) void prep_xt(const float* __restrict__ x,
                                               unsigned short* __restrict__ ws)
{
    const int gid = blockIdx.x*256 + threadIdx.x;   // < 1048576
    const int b = gid >> 17, rem = gid & 131071, r = rem >> 11, cd = rem & 2047;
    const float v = x[gid];
    const int o = (b*2048 + cd)*64 + r;
    split_bf(v, ws + XTHI + o, ws + XTLO + o);
}

// ---------- prep: K = x @ kW + kb (fp32 VALU), split-stored ----------
__device__ __forceinline__ void mm16f(const float* __restrict__ shX,
                                      const float* __restrict__ W,
                                      const float* __restrict__ bias,
                                      int t, float acc[8])
{
    const int c = t & 15, jg = t >> 4;
    const float4 b0 = *reinterpret_cast<const float4*>(bias + jg*8);
    const float4 b1 = *reinterpret_cast<const float4*>(bias + jg*8 + 4);
    acc[0]=b0.x; acc[1]=b0.y; acc[2]=b0.z; acc[3]=b0.w;
    acc[4]=b1.x; acc[5]=b1.y; acc[6]=b1.z; acc[7]=b1.w;
    const float* Wp = W + jg*8;
    const float* xrow = shX + c*LSTR;
    #pragma unroll 4
    for (int k = 0; k < 128; ++k){
        const float xv = xrow[k];
        const float4 w0 = *reinterpret_cast<const float4*>(Wp + k*128);
        const float4 w1 = *reinterpret_cast<const float4*>(Wp + k*128 + 4);
        acc[0] = fmaf(xv, w0.x, acc[0]); acc[1] = fmaf(xv, w0.y, acc[1]);
        acc[2] = fmaf(xv, w0.z, acc[2]); acc[3] = fmaf(xv, w0.w, acc[3]);
        acc[4] = fmaf(xv, w1.x, acc[4]); acc[5] = fmaf(xv, w1.y, acc[5]);
        acc[6] = fmaf(xv, w1.z, acc[6]); acc[7] = fmaf(xv, w1.w, acc[7]);
    }
}

__global__ __launch_bounds__(256) void k_prep(const float* __restrict__ x,
        const float* __restrict__ kW, const float* __restrict__ kb,
        unsigned short* __restrict__ ws)
{
    __shared__ float shX[C_*LSTR];
    const int t = threadIdx.x;
    const long base = (long)blockIdx.x * CD;
    const float* xp = x + base;
    {
        const int pos = 8*t, cc0 = pos >> 7, d0 = pos & 127;
        const float4 v0 = *reinterpret_cast<const float4*>(xp + pos);
        const float4 v1 = *reinterpret_cast<const float4*>(xp + pos + 4);
        float* dst = &shX[cc0*LSTR + d0];
        *reinterpret_cast<float4*>(dst)     = v0;
        *reinterpret_cast<float4*>(dst + 4) = v1;
    }
    __syncthreads();
    float acc[8];
    mm16f(shX, kW, kb, t, acc);
    const int c = t & 15, jg = t >> 4;
    const long o = base + c*128 + jg*8;
    #pragma unroll
    for (int jj = 0; jj < 8; ++jj)
        split_bf(acc[jj], ws + KHI + o + jj, ws + KLO + o + jj);
}

// ---------- W-GEMM helper: M=64 (4 m-tiles), N=128 (wave w owns n-tiles 2w,2w+1), K=128 ----------
__device__ __forceinline__ void gemm_W(const unsigned short* sA_hi, const unsigned short* sA_lo,
                                       const unsigned short* WT_hi, const unsigned short* WT_lo,
                                       const float* __restrict__ bias,
                                       int w, int lane, float4v acc[8])
{
    const int l15 = lane & 15, quad = lane >> 4;
    #pragma unroll
    for (int nt = 0; nt < 2; ++nt){
        const float bv = bias[(2*w+nt)*16 + l15];
        #pragma unroll
        for (int mt = 0; mt < 4; ++mt){ float4v d = {bv,bv,bv,bv}; acc[nt*4+mt] = d; }
    }
    #pragma unroll
    for (int ks = 0; ks < 4; ++ks){
        const int ko = ks*32 + quad*8;
        short8 a_hi[4], a_lo[4], b_hi[2], b_lo[2];
        #pragma unroll
        for (int mt = 0; mt < 4; ++mt){
            const int ad = (mt*16 + l15)*136 + ko;
            a_hi[mt] = *reinterpret_cast<const short8*>(sA_hi + ad);
            a_lo[mt] = *reinterpret_cast<const short8*>(sA_lo + ad);
        }
        #pragma unroll
        for (int nt = 0; nt < 2; ++nt){
            const int bd = ((2*w+nt)*16 + l15)*128 + ko;
            b_hi[nt] = *reinterpret_cast<const short8*>(WT_hi + bd);
            b_lo[nt] = *reinterpret_cast<const short8*>(WT_lo + bd);
        }
        #pragma unroll
        for (int nt = 0; nt < 2; ++nt)
        #pragma unroll
        for (int mt = 0; mt < 4; ++mt){
            float4v d = acc[nt*4+mt];
            d = __builtin_amdgcn_mfma_f32_16x16x32_bf16(a_hi[mt], b_hi[nt], d, 0,0,0);
            d = __builtin_amdgcn_mfma_f32_16x16x32_bf16(a_hi[mt], b_lo[nt], d, 0,0,0);
            d = __builtin_amdgcn_mfma_f32_16x16x32_bf16(a_lo[mt], b_hi[nt], d, 0,0,0);
            acc[nt*4+mt] = d;
        }
    }
}

// ---------- main fused kernel: block = (pair-group of 4, batch) ----------
__global__ __launch_bounds__(256,2) void k_main(
    const float* __restrict__ x, const float* __restrict__ seq_mask,
    const int* __restrict__ row, const int* __restrict__ col,
    const float* __restrict__ hb, const float* __restrict__ qb,
    const float* __restrict__ gb, const float* __restrict__ s1b,
    const float* __restrict__ s2W, const float* __restrict__ s2b,
    const unsigned short* __restrict__ ws, float* __restrict__ out)
{
    __shared__ __align__(16) unsigned short sX_hi[64*136];
    __shared__ __align__(16) unsigned short sX_lo[64*136];
    __shared__ __align__(16) unsigned short sU_hi[64*136];   // union: Q (4 rows, stride 2056) then XG (64x136)
    __shared__ __align__(16) unsigned short sU_lo[64*136];
    __shared__ __align__(16) unsigned short sAl_hi[16*72];
    __shared__ __align__(16) unsigned short sAl_lo[16*72];
    __shared__ float sLog[4*64];
    __shared__ float sS[64];

    const int t = threadIdx.x;
    const int w = t >> 6, lane = t & 63, l15 = lane & 15, quad = lane >> 4;
    const int p0 = blockIdx.x * PG, b = blockIdx.y;
    const float* xb = x + (size_t)b * R_ * CD;

    const int rp0 = row[p0+0], rp1 = row[p0+1], rp2 = row[p0+2], rp3 = row[p0+3];
    const int cp0 = col[p0+0], cp1 = col[p0+1], cp2 = col[p0+2], cp3 = col[p0+3];

    // zero alphaW (rows >=4 must be 0) and sS
    for (int i = t; i < 16*72; i += 256){ sAl_hi[i] = 0; sAl_lo[i] = 0; }
    if (t < 64) sS[t] = 0.f;

    // ---- stage diff = xi - xj (split bf16) into sX ----
    #pragma unroll
    for (int i = 0; i < 8; ++i){
        const int f4 = t + 256*i;          // 0..2047
        const int flat = f4*4;             // 0..8188
        const int p = flat >> 11;
        const int cd = flat & 2047;
        const int ridx = sel4(p, rp0, rp1, rp2, rp3);
        const int cidx = sel4(p, cp0, cp1, cp2, cp3);
        const float4 a  = *reinterpret_cast<const float4*>(xb + (size_t)ridx*CD + cd);
        const float4 bb = *reinterpret_cast<const float4*>(xb + (size_t)cidx*CD + cd);
        const int base = (p*16 + (cd>>7))*136 + (cd & 127);
        split_bf(a.x - bb.x, sX_hi+base+0, sX_lo+base+0);
        split_bf(a.y - bb.y, sX_hi+base+1, sX_lo+base+1);
        split_bf(a.z - bb.z, sX_hi+base+2, sX_lo+base+2);
        split_bf(a.w - bb.w, sX_hi+base+3, sX_lo+base+3);
    }
    __syncthreads();

    float4v acc[8];

    // ---- h-GEMM + gating epilogue: x = xj + z*diff  (overwrite sX) ----
    gemm_W(sX_hi, sX_lo, ws+WTHI, ws+WTLO, hb, w, lane, acc);
    __syncthreads();   // all MFMA reads of diff done before overwrite
    #pragma unroll
    for (int nt = 0; nt < 2; ++nt){
        const int colg = (2*w+nt)*16 + l15;
        #pragma unroll
        for (int mt = 0; mt < 4; ++mt){
            const int cidx = sel4(mt, cp0, cp1, cp2, cp3);
            #pragma unroll
            for (int e = 0; e < 4; ++e){
                const int c = quad*4 + e;
                const int rowi = mt*16 + c;
                const int ad = rowi*136 + colg;
                const float z = sigmoid_safe(acc[nt*4+mt][e]);
                const float diff = join_bf(sX_hi[ad], sX_lo[ad]);
                const float xjv = xb[(size_t)cidx*CD + c*128 + colg];
                split_bf(xjv + z*diff, sX_hi+ad, sX_lo+ad);
            }
        }
    }
    __syncthreads();

    // ---- q-GEMM, write Q[pair][cd] (stride 2056) into sU ----
    gemm_W(sX_hi, sX_lo, ws+WTHI+16384, ws+WTLO+16384, qb, w, lane, acc);
    #pragma unroll
    for (int nt = 0; nt < 2; ++nt){
        const int colg = (2*w+nt)*16 + l15;
        #pragma unroll
        for (int mt = 0; mt < 4; ++mt)
        #pragma unroll
        for (int e = 0; e < 4; ++e){
            const int c = quad*4 + e;
            const int qd = mt*2056 + c*128 + colg;
            split_bf(acc[nt*4+mt][e], sU_hi+qd, sU_lo+qd);
        }
    }
    __syncthreads();

    // ---- alpha GEMM: logits[pair][r] = q . K[b,r]  (M-tile 1, wave w -> r-tile w, K=2048) ----
    {
        const unsigned short* Kh = ws + KHI + (size_t)b*64*2048;
        const unsigned short* Kl = ws + KLO + (size_t)b*64*2048;
        const int pr = l15 & 3;                 // duplicate pairs into rows 4..15 (ignored)
        const int abase = pr*2056;
        const int bbase = (w*16 + l15)*2048;
        float4v d = {0.f,0.f,0.f,0.f};
        #pragma unroll 4
        for (int ks = 0; ks < 64; ++ks){
            const int ko = ks*32 + quad*8;
            const short8 ah = *reinterpret_cast<const short8*>(sU_hi + abase + ko);
            const short8 al = *reinterpret_cast<const short8*>(sU_lo + abase + ko);
            const short8 bh = *reinterpret_cast<const short8*>(Kh + bbase + ko);
            const short8 bl = *reinterpret_cast<const short8*>(Kl + bbase + ko);
            d = __builtin_amdgcn_mfma_f32_16x16x32_bf16(ah, bh, d, 0,0,0);
            d = __builtin_amdgcn_mfma_f32_16x16x32_bf16(ah, bl, d, 0,0,0);
            d = __builtin_amdgcn_mfma_f32_16x16x32_bf16(al, bh, d, 0,0,0);
        }
        #pragma unroll
        for (int e = 0; e < 4; ++e){
            const int pp = quad*4 + e;
            if (pp < 4) sLog[pp*64 + w*16 + l15] = d[e] * SCALE;
        }
    }
    __syncthreads();

    // ---- masked softmax over r (threads 0..63: 16 lanes per pair, 4 r's each) ----
    if (t < 64){
        const int pp = t >> 4, l = t & 15;
        const int ri = sel4(pp, rp0, rp1, rp2, rp3);
        const int ci = sel4(pp, cp0, cp1, cp2, cp3);
        float v[4]; float m = NEG_BIG;
        #pragma unroll
        for (int k = 0; k < 4; ++k){
            const int r = l + 16*k;
            float lv = sLog[pp*64 + r];
            if (r == ri || r == ci) lv = NEG_BIG;
            v[k] = lv; m = fmaxf(m, lv);
        }
        #pragma unroll
        for (int s = 1; s < 16; s <<= 1) m = fmaxf(m, __shfl_xor(m, s));
        float e4[4]; float sum = 0.f;
        #pragma unroll
        for (int k = 0; k < 4; ++k){
            const int r = l + 16*k;
            const bool masked = (r == ri || r == ci);
            const float e = masked ? 0.f : __expf(fmaxf(v[k]-m, -80.f));
            e4[k] = e; sum += e;
        }
        #pragma unroll
        for (int s = 1; s < 16; s <<= 1) sum += __shfl_xor(sum, s);
        const float inv = 1.f / sum;
        #pragma unroll
        for (int k = 0; k < 4; ++k){
            const int r = l + 16*k;
            split_bf(e4[k]*inv, sAl_hi + pp*72 + r, sAl_lo + pp*72 + r);
        }
    }
    __syncthreads();

    // ---- x_glob GEMM: XG[pair][cd] = alpha @ Xall   (K=64, wave w -> 32 n-tiles) ----
    {
        const unsigned short* XTh = ws + XTHI + (size_t)b*2048*64;
        const unsigned short* XTl = ws + XTLO + (size_t)b*2048*64;
        short8 Ah[2], Al[2];
        #pragma unroll
        for (int ks = 0; ks < 2; ++ks){
            const int ko = ks*32 + quad*8;
            Ah[ks] = *reinterpret_cast<const short8*>(sAl_hi + l15*72 + ko);
            Al[ks] = *reinterpret_cast<const short8*>(sAl_lo + l15*72 + ko);
        }
        for (int j = 0; j < 32; ++j){
            const int n0 = (w*32 + j)*16;
            float4v d = {0.f,0.f,0.f,0.f};
            #pragma unroll
            for (int ks = 0; ks < 2; ++ks){
                const int ko = ks*32 + quad*8;
                const short8 bh = *reinterpret_cast<const short8*>(XTh + (n0+l15)*64 + ko);
                const short8 bl = *reinterpret_cast<const short8*>(XTl + (n0+l15)*64 + ko);
                d = __builtin_amdgcn_mfma_f32_16x16x32_bf16(Ah[ks], bh, d, 0,0,0);
                d = __builtin_amdgcn_mfma_f32_16x16x32_bf16(Ah[ks], bl, d, 0,0,0);
                d = __builtin_amdgcn_mfma_f32_16x16x32_bf16(Al[ks], bh, d, 0,0,0);
            }
            const int cd = n0 + l15;
            const int rbase = (cd>>7), dd = cd & 127;
            #pragma unroll
            for (int e = 0; e < 4; ++e){
                const int pp = quad*4 + e;
                if (pp < 4){
                    const int ad = (pp*16 + rbase)*136 + dd;
                    split_bf(d[e], sU_hi+ad, sU_lo+ad);   // Q is dead; reuse as XG (A-layout)
                }
            }
        }
    }
    __syncthreads();

    // ---- g-GEMM + gate epilogue: x = (1-w)*x + w*xg  (overwrite sX) ----
    gemm_W(sU_hi, sU_lo, ws+WTHI+32768, ws+WTLO+32768, gb, w, lane, acc);
    #pragma unroll
    for (int nt = 0; nt < 2; ++nt){
        const int colg = (2*w+nt)*16 + l15;
        #pragma unroll
        for (int mt = 0; mt < 4; ++mt)
        #pragma unroll
        for (int e = 0; e < 4; ++e){
            const int rowi = mt*16 + quad*4 + e;
            const int ad = rowi*136 + colg;
            const float wv = sigmoid_safe(acc[nt*4+mt][e]);
            const float xv  = join_bf(sX_hi[ad], sX_lo[ad]);
            const float xgv = join_bf(sU_hi[ad], sU_lo[ad]);
            split_bf((1.f - wv)*xv + wv*xgv, sX_hi+ad, sX_lo+ad);
        }
    }
    __syncthreads();

    // ---- s1-GEMM + gelu + s2 reduction ----
    gemm_W(sX_hi, sX_lo, ws+WTHI+49152, ws+WTLO+49152, s1b, w, lane, acc);
    #pragma unroll
    for (int nt = 0; nt < 2; ++nt){
        const int colg = (2*w+nt)*16 + l15;
        const float s2v = s2W[colg];
        #pragma unroll
        for (int mt = 0; mt < 4; ++mt)
        #pragma unroll
        for (int e = 0; e < 4; ++e){
            const int rowi = mt*16 + quad*4 + e;
            const float tv = acc[nt*4+mt][e];
            const float gl = 0.5f * tv * (1.f + erff(tv * 0.70710678118654752f));
            float part = gl * s2v;
            #pragma unroll
            for (int s = 1; s < 16; s <<= 1) part += __shfl_xor(part, s);
            if (l15 == 0) atomicAdd(&sS[rowi], part);
        }
    }
    __syncthreads();

    if (t < PG){
        const float s2bv = s2b[0];
        float o = 0.f;
        #pragma unroll
        for (int c = 0; c < 16; ++c)
            o += (sS[t*16 + c] + s2bv) * seq_mask[b*C_ + c];
        out[(size_t)b*NPAIR + p0 + t] = o;
    }
}

extern "C" void kernel_launch(void* const* d_in, const int* in_sizes, int n_in,
                              void* d_out, int out_size, void* d_ws, size_t ws_size,
                              hipStream_t stream)
{
    const float* x    = (const float*)d_in[0];
    const float* mask = (const float*)d_in[1];
    const int*   row  = (const int*)d_in[2];
    const int*   col  = (const int*)d_in[3];
    const float* hW  = (const float*)d_in[4];  const float* hb  = (const float*)d_in[5];
    const float* gW  = (const float*)d_in[6];  const float* gb  = (const float*)d_in[7];
    const float* qW  = (const float*)d_in[8];  const float* qb  = (const float*)d_in[9];
    const float* kW  = (const float*)d_in[10]; const float* kb  = (const float*)d_in[11];
    const float* s1W = (const float*)d_in[12]; const float* s1b = (const float*)d_in[13];
    const float* s2W = (const float*)d_in[14]; const float* s2b = (const float*)d_in[15];

    unsigned short* ws = (unsigned short*)d_ws;   // ~8.65 MB used

    prep_wt<<<256, 256, 0, stream>>>(hW, qW, gW, s1W, ws);
    prep_xt<<<4096, 256, 0, stream>>>(x, ws);
    k_prep <<<B_*R_, 256, 0, stream>>>(x, kW, kb, ws);
    k_main <<<dim3(NPAIR/PG, B_), 256, 0, stream>>>(x, mask, row, col,
                                                    hb, qb, gb, s1b, s2W, s2b,
                                                    ws, (float*)d_out);
}

// Round 5
// 460.091 us; speedup vs baseline: 5.4985x; 1.6368x over previous
//
#include <hip/hip_runtime.h>
#include <hip/hip_bf16.h>
#include <math.h>

#define B_    8
#define R_    64
#define C_    16
#define D_    128
#define NPAIR 2016
#define CD    2048
#define PG    4
#define LSTR  132    // fp32 LDS stride in k_prep role
#define XSTR  136    // bf16 tile row stride (16B-aligned, 68-dword rows)
#define NEG_BIG (-1e30f)
#define SCALE 0.022097086912079608f   // 1/sqrt(2048)

typedef __attribute__((ext_vector_type(8))) short short8;
typedef __attribute__((ext_vector_type(4))) float float4v;

// ---- workspace layout (ushort element offsets) ----
// WT hi/lo: 4 mats x 128n x 128k
#define WTHI 0u
#define WTLO 65536u
#define KHI  131072u     // K[b][r][cd] bf16: 8*64*2048 = 1048576
#define XTHI 1179648u    // XT[b][cd][r] bf16: 8*2048*64 = 1048576
// total 2228224 ushorts = 4.46 MB

__device__ __forceinline__ unsigned short f2b(float v){
    __hip_bfloat16 h = __float2bfloat16(v);
    return *reinterpret_cast<unsigned short*>(&h);
}
__device__ __forceinline__ float b2f(unsigned short u){
    union { unsigned int i; float f; } v; v.i = ((unsigned int)u) << 16; return v.f;
}
__device__ __forceinline__ unsigned int pack2(float a, float b){
    return (unsigned int)f2b(a) | ((unsigned int)f2b(b) << 16);
}
__device__ __forceinline__ void split_bf(float v, unsigned short* hi, unsigned short* lo){
    __hip_bfloat16 h = __float2bfloat16(v);
    float hf = __bfloat162float(h);
    __hip_bfloat16 l = __float2bfloat16(v - hf);
    *hi = *reinterpret_cast<unsigned short*>(&h);
    *lo = *reinterpret_cast<unsigned short*>(&l);
}
__device__ __forceinline__ float sigmoid_safe(float x){
    x = fminf(fmaxf(x, -30.f), 30.f);
    return 1.f / (1.f + __expf(-x));
}
__device__ __forceinline__ int sel4(int i, int a, int b, int c, int d){
    return i==0 ? a : (i==1 ? b : (i==2 ? c : d));
}

// fp32 VALU 16x128 @ 128x128 (k_prep role only)
__device__ __forceinline__ void mm16f(const float* __restrict__ shX,
                                      const float* __restrict__ W,
                                      const float* __restrict__ bias,
                                      int t, float acc[8])
{
    const int c = t & 15, jg = t >> 4;
    const float4 b0 = *reinterpret_cast<const float4*>(bias + jg*8);
    const float4 b1 = *reinterpret_cast<const float4*>(bias + jg*8 + 4);
    acc[0]=b0.x; acc[1]=b0.y; acc[2]=b0.z; acc[3]=b0.w;
    acc[4]=b1.x; acc[5]=b1.y; acc[6]=b1.z; acc[7]=b1.w;
    const float* Wp = W + jg*8;
    const float* xrow = shX + c*LSTR;
    #pragma unroll 4
    for (int k = 0; k < 128; ++k){
        const float xv = xrow[k];
        const float4 w0 = *reinterpret_cast<const float4*>(Wp + k*128);
        const float4 w1 = *reinterpret_cast<const float4*>(Wp + k*128 + 4);
        acc[0] = fmaf(xv, w0.x, acc[0]); acc[1] = fmaf(xv, w0.y, acc[1]);
        acc[2] = fmaf(xv, w0.z, acc[2]); acc[3] = fmaf(xv, w0.w, acc[3]);
        acc[4] = fmaf(xv, w1.x, acc[4]); acc[5] = fmaf(xv, w1.y, acc[5]);
        acc[6] = fmaf(xv, w1.z, acc[6]); acc[7] = fmaf(xv, w1.w, acc[7]);
    }
}

// ---------- merged prep: [0,512) K-GEMM | [512,768) WT split | [768,4864) XT ----------
__global__ __launch_bounds__(256) void k_prep_all(
    const float* __restrict__ x,
    const float* __restrict__ hW, const float* __restrict__ qW,
    const float* __restrict__ gW, const float* __restrict__ s1W,
    const float* __restrict__ kW, const float* __restrict__ kb,
    unsigned short* __restrict__ ws)
{
    __shared__ float shX[C_*LSTR];
    const int bid = blockIdx.x, t = threadIdx.x;
    if (bid < 512){
        // K[b][r] = x[b,r] @ kW + kb, store bf16
        const long base = (long)bid * CD;
        const float* xp = x + base;
        {
            const int pos = 8*t, cc0 = pos >> 7, d0 = pos & 127;
            const float4 v0 = *reinterpret_cast<const float4*>(xp + pos);
            const float4 v1 = *reinterpret_cast<const float4*>(xp + pos + 4);
            float* dst = &shX[cc0*LSTR + d0];
            *reinterpret_cast<float4*>(dst)     = v0;
            *reinterpret_cast<float4*>(dst + 4) = v1;
        }
        __syncthreads();
        float acc[8];
        mm16f(shX, kW, kb, t, acc);
        const int c = t & 15, jg = t >> 4;
        const long o = base + c*128 + jg*8;
        #pragma unroll
        for (int jj = 0; jj < 8; ++jj) ws[KHI + o + jj] = f2b(acc[jj]);
    } else if (bid < 768){
        // WT[mat][n][k] split hi/lo
        const int gid = (bid-512)*256 + t;                   // < 65536
        const int mat = gid >> 14, rem = gid & 16383, n = rem >> 7, k = rem & 127;
        const float* W = (mat==0) ? hW : (mat==1) ? qW : (mat==2) ? gW : s1W;
        split_bf(W[k*128 + n], ws + WTHI + gid, ws + WTLO + gid);
    } else {
        // XT[b][cd][r] bf16
        const int gid = (bid-768)*256 + t;                   // < 1048576
        const int b = gid >> 17, rem = gid & 131071, r = rem >> 11, cd = rem & 2047;
        ws[XTHI + (b*2048 + cd)*64 + r] = f2b(x[gid]);
    }
}

// ---------- W-GEMM: A bf16 in LDS (64x128 tile, stride XSTR), B split-bf16 weights ----------
__device__ __forceinline__ void gemm_W(const unsigned short* sA,
                                       const unsigned short* WT_hi, const unsigned short* WT_lo,
                                       const float* __restrict__ bias,
                                       int w, int lane, float4v acc[8])
{
    const int l15 = lane & 15, quad = lane >> 4;
    #pragma unroll
    for (int nt = 0; nt < 2; ++nt){
        const float bv = bias[(2*w+nt)*16 + l15];
        #pragma unroll
        for (int mt = 0; mt < 4; ++mt){ float4v d = {bv,bv,bv,bv}; acc[nt*4+mt] = d; }
    }
    #pragma unroll
    for (int ks = 0; ks < 4; ++ks){
        const int ko = ks*32 + quad*8;
        short8 a[4], b_hi[2], b_lo[2];
        #pragma unroll
        for (int mt = 0; mt < 4; ++mt)
            a[mt] = *reinterpret_cast<const short8*>(sA + (mt*16 + l15)*XSTR + ko);
        #pragma unroll
        for (int nt = 0; nt < 2; ++nt){
            const int bd = ((2*w+nt)*16 + l15)*128 + ko;
            b_hi[nt] = *reinterpret_cast<const short8*>(WT_hi + bd);
            b_lo[nt] = *reinterpret_cast<const short8*>(WT_lo + bd);
        }
        #pragma unroll
        for (int nt = 0; nt < 2; ++nt)
        #pragma unroll
        for (int mt = 0; mt < 4; ++mt){
            float4v d = acc[nt*4+mt];
            d = __builtin_amdgcn_mfma_f32_16x16x32_bf16(a[mt], b_hi[nt], d, 0,0,0);
            d = __builtin_amdgcn_mfma_f32_16x16x32_bf16(a[mt], b_lo[nt], d, 0,0,0);
            acc[nt*4+mt] = d;
        }
    }
}

// ---------- main fused kernel ----------
__global__ __launch_bounds__(256,4) void k_main(
    const float* __restrict__ x, const float* __restrict__ seq_mask,
    const int* __restrict__ row, const int* __restrict__ col,
    const float* __restrict__ hb, const float* __restrict__ qb,
    const float* __restrict__ gb, const float* __restrict__ s1b,
    const float* __restrict__ s2W, const float* __restrict__ s2b,
    const unsigned short* __restrict__ ws, float* __restrict__ out)
{
    __shared__ __align__(16) unsigned short sX[64*XSTR];  // diff -> x state
    __shared__ __align__(16) unsigned short sU[64*XSTR];  // xj -> Q -> XG
    __shared__ __align__(16) unsigned short sAl[16*72];
    __shared__ float sLog[4*64];
    __shared__ float sS[64];

    const int t = threadIdx.x;
    const int w = t >> 6, lane = t & 63, l15 = lane & 15, quad = lane >> 4;
    const int p0 = blockIdx.x * PG, b = blockIdx.y;
    const float* xb = x + (size_t)b * R_ * CD;

    const int rp0 = row[p0+0], rp1 = row[p0+1], rp2 = row[p0+2], rp3 = row[p0+3];
    const int cp0 = col[p0+0], cp1 = col[p0+1], cp2 = col[p0+2], cp3 = col[p0+3];

    for (int i = t; i < 16*72; i += 256) sAl[i] = 0;
    if (t < 64) sS[t] = 0.f;

    // ---- stage diff -> sX, xj -> sU (bf16) ----
    #pragma unroll
    for (int i = 0; i < 8; ++i){
        const int f4 = t + 256*i;          // 0..2047
        const int flat = f4*4;
        const int p = flat >> 11, cd = flat & 2047;
        const int ridx = sel4(p, rp0, rp1, rp2, rp3);
        const int cidx = sel4(p, cp0, cp1, cp2, cp3);
        const float4 a  = *reinterpret_cast<const float4*>(xb + (size_t)ridx*CD + cd);
        const float4 bb = *reinterpret_cast<const float4*>(xb + (size_t)cidx*CD + cd);
        const int base = (p*16 + (cd>>7))*XSTR + (cd & 127);
        uint2 dv, jv;
        dv.x = pack2(a.x-bb.x, a.y-bb.y); dv.y = pack2(a.z-bb.z, a.w-bb.w);
        jv.x = pack2(bb.x, bb.y);         jv.y = pack2(bb.z, bb.w);
        *reinterpret_cast<uint2*>(sX + base) = dv;
        *reinterpret_cast<uint2*>(sU + base) = jv;
    }
    __syncthreads();

    float4v acc[8];

    // ---- h-GEMM + gate: x = xj + z*diff (overwrite sX) ----
    gemm_W(sX, ws+WTHI, ws+WTLO, hb, w, lane, acc);
    __syncthreads();   // all MFMA reads of diff complete before overwrite
    #pragma unroll
    for (int nt = 0; nt < 2; ++nt){
        const int colg = (2*w+nt)*16 + l15;
        #pragma unroll
        for (int mt = 0; mt < 4; ++mt)
        #pragma unroll
        for (int e = 0; e < 4; ++e){
            const int c = quad*4 + e;
            const int ad = (mt*16 + c)*XSTR + colg;
            const float z = sigmoid_safe(acc[nt*4+mt][e]);
            sX[ad] = f2b(b2f(sU[ad]) + z * b2f(sX[ad]));
        }
    }
    __syncthreads();

    // ---- q-GEMM -> Q into sU (tile layout, xj dead) ----
    gemm_W(sX, ws+WTHI+16384, ws+WTLO+16384, qb, w, lane, acc);
    #pragma unroll
    for (int nt = 0; nt < 2; ++nt){
        const int colg = (2*w+nt)*16 + l15;
        #pragma unroll
        for (int mt = 0; mt < 4; ++mt)
        #pragma unroll
        for (int e = 0; e < 4; ++e){
            const int c = quad*4 + e;
            sU[(mt*16 + c)*XSTR + colg] = f2b(acc[nt*4+mt][e]);
        }
    }
    __syncthreads();

    // ---- alpha GEMM: logits[p][r] = q.K[b,r], K=2048, wave w -> r in [16w,16w+16) ----
    {
        const unsigned short* Kb = ws + KHI + (size_t)b * 64 * 2048;
        const int pr = l15 & 3;                // pairs replicated across l15 (broadcast reads)
        const int rrow = w*16 + l15;
        const unsigned short* Kr = Kb + (size_t)rrow * 2048;
        float4v d = {0.f,0.f,0.f,0.f};
        #pragma unroll 8
        for (int ks = 0; ks < 64; ++ks){
            const int k = ks*32 + quad*8;
            const short8 ah = *reinterpret_cast<const short8*>(sU + (pr*16 + (k>>7))*XSTR + (k&127));
            const short8 bh = *reinterpret_cast<const short8*>(Kr + k);
            d = __builtin_amdgcn_mfma_f32_16x16x32_bf16(ah, bh, d, 0,0,0);
        }
        #pragma unroll
        for (int e = 0; e < 4; ++e){
            const int pp = quad*4 + e;
            if (pp < 4) sLog[pp*64 + rrow] = d[e] * SCALE;
        }
    }
    __syncthreads();

    // ---- masked softmax (threads 0..63: 16 lanes per pair) ----
    if (t < 64){
        const int pp = t >> 4, l = t & 15;
        const int ri = sel4(pp, rp0, rp1, rp2, rp3);
        const int ci = sel4(pp, cp0, cp1, cp2, cp3);
        float v[4]; float m = NEG_BIG;
        #pragma unroll
        for (int k = 0; k < 4; ++k){
            const int r = l + 16*k;
            float lv = sLog[pp*64 + r];
            if (r == ri || r == ci) lv = NEG_BIG;
            v[k] = lv; m = fmaxf(m, lv);
        }
        #pragma unroll
        for (int s = 1; s < 16; s <<= 1) m = fmaxf(m, __shfl_xor(m, s));
        float e4[4]; float sum = 0.f;
        #pragma unroll
        for (int k = 0; k < 4; ++k){
            const int r = l + 16*k;
            const bool masked = (r == ri || r == ci);
            const float e = masked ? 0.f : __expf(fmaxf(v[k]-m, -80.f));
            e4[k] = e; sum += e;
        }
        #pragma unroll
        for (int s = 1; s < 16; s <<= 1) sum += __shfl_xor(sum, s);
        const float inv = 1.f / sum;
        #pragma unroll
        for (int k = 0; k < 4; ++k) sAl[pp*72 + l + 16*k] = f2b(e4[k]*inv);
    }
    __syncthreads();

    // ---- x_glob GEMM: XG[p][cd] = alpha @ X, K=64; wave w -> cd in [512w, 512w+512) ----
    {
        const unsigned short* XTb = ws + XTHI + (size_t)b * 2048 * 64;
        short8 Ah[2];
        #pragma unroll
        for (int ks = 0; ks < 2; ++ks)
            Ah[ks] = *reinterpret_cast<const short8*>(sAl + l15*72 + ks*32 + quad*8);
        for (int j = 0; j < 32; ++j){
            const int n0 = (w*32 + j)*16;
            const int cd = n0 + l15;
            float4v d = {0.f,0.f,0.f,0.f};
            #pragma unroll
            for (int ks = 0; ks < 2; ++ks){
                const short8 bh = *reinterpret_cast<const short8*>(XTb + (size_t)cd*64 + ks*32 + quad*8);
                d = __builtin_amdgcn_mfma_f32_16x16x32_bf16(Ah[ks], bh, d, 0,0,0);
            }
            if (quad == 0){
                #pragma unroll
                for (int e = 0; e < 4; ++e)
                    sU[(e*16 + (cd>>7))*XSTR + (cd&127)] = f2b(d[e]);  // Q dead -> XG
            }
        }
    }
    __syncthreads();

    // ---- g-GEMM + gate: x = (1-w)*x + w*xg (overwrite sX) ----
    gemm_W(sU, ws+WTHI+32768, ws+WTLO+32768, gb, w, lane, acc);
    #pragma unroll
    for (int nt = 0; nt < 2; ++nt){
        const int colg = (2*w+nt)*16 + l15;
        #pragma unroll
        for (int mt = 0; mt < 4; ++mt)
        #pragma unroll
        for (int e = 0; e < 4; ++e){
            const int ad = (mt*16 + quad*4 + e)*XSTR + colg;
            const float wv = sigmoid_safe(acc[nt*4+mt][e]);
            sX[ad] = f2b((1.f - wv)*b2f(sX[ad]) + wv*b2f(sU[ad]));
        }
    }
    __syncthreads();

    // ---- s1-GEMM + gelu + s2 reduce ----
    gemm_W(sX, ws+WTHI+49152, ws+WTLO+49152, s1b, w, lane, acc);
    #pragma unroll
    for (int nt = 0; nt < 2; ++nt){
        const int colg = (2*w+nt)*16 + l15;
        const float s2v = s2W[colg];
        #pragma unroll
        for (int mt = 0; mt < 4; ++mt)
        #pragma unroll
        for (int e = 0; e < 4; ++e){
            const int rowi = mt*16 + quad*4 + e;
            const float tv = acc[nt*4+mt][e];
            const float gl = 0.5f * tv * (1.f + erff(tv * 0.70710678118654752f));
            float part = gl * s2v;
            #pragma unroll
            for (int s = 1; s < 16; s <<= 1) part += __shfl_xor(part, s);
            if (l15 == 0) atomicAdd(&sS[rowi], part);
        }
    }
    __syncthreads();

    if (t < PG){
        const float s2bv = s2b[0];
        float o = 0.f;
        #pragma unroll
        for (int c = 0; c < 16; ++c)
            o += (sS[t*16 + c] + s2bv) * seq_mask[b*C_ + c];
        out[(size_t)b*NPAIR + p0 + t] = o;
    }
}

extern "C" void kernel_launch(void* const* d_in, const int* in_sizes, int n_in,
                              void* d_out, int out_size, void* d_ws, size_t ws_size,
                              hipStream_t stream)
{
    const float* x    = (const float*)d_in[0];
    const float* mask = (const float*)d_in[1];
    const int*   row  = (const int*)d_in[2];
    const int*   col  = (const int*)d_in[3];
    const float* hW  = (const float*)d_in[4];  const float* hb  = (const float*)d_in[5];
    const float* gW  = (const float*)d_in[6];  const float* gb  = (const float*)d_in[7];
    const float* qW  = (const float*)d_in[8];  const float* qb  = (const float*)d_in[9];
    const float* kW  = (const float*)d_in[10]; const float* kb  = (const float*)d_in[11];
    const float* s1W = (const float*)d_in[12]; const float* s1b = (const float*)d_in[13];
    const float* s2W = (const float*)d_in[14]; const float* s2b = (const float*)d_in[15];

    unsigned short* ws = (unsigned short*)d_ws;   // 4.46 MB used

    k_prep_all<<<4864, 256, 0, stream>>>(x, hW, qW, gW, s1W, kW, kb, ws);
    k_main<<<dim3(NPAIR/PG, B_), 256, 0, stream>>>(x, mask, row, col,
                                                   hb, qb, gb, s1b, s2W, s2b,
                                                   ws, (float*)d_out);
}

// Round 6
// 321.945 us; speedup vs baseline: 7.8579x; 1.4291x over previous
//
#include <hip/hip_runtime.h>
#include <hip/hip_bf16.h>
#include <math.h>

#define B_    8
#define R_    64
#define C_    16
#define D_    128
#define NPAIR 2016
#define CD    2048
#define PG    8
#define LSTR  132
#define XSTR  136
#define NEG_BIG (-1e30f)
#define SCALE 0.022097086912079608f   // 1/sqrt(2048)

typedef __attribute__((ext_vector_type(8))) short short8;
typedef __attribute__((ext_vector_type(4))) float float4v;

// ---- ws layout (ushort offsets) ----
#define MWF   0u        // fp32 MW2[128][128]  (32768 ushorts)
#define MBF   32768u    // fp32 mb[128]
#define KQF   33024u    // fp32 kq[128]
#define S0F   33280u    // fp32 s0
#define QBK   33282u    // fp32 qbk[512]
#define WTHI  34320u    // bf16-hi: h,g,s1  3*16384
#define WTLO  83472u    // bf16-lo
#define MMAT  132624u   // bf16 M[8][64][2048]
#define XTO   1181200u  // bf16 XT[8][2048][64]
// total 2229776 ushorts = 4.46 MB

__device__ __forceinline__ unsigned short f2b(float v){
    __hip_bfloat16 h = __float2bfloat16(v);
    return *reinterpret_cast<unsigned short*>(&h);
}
__device__ __forceinline__ float b2f(unsigned short u){
    union { unsigned int i; float f; } v; v.i = ((unsigned int)u) << 16; return v.f;
}
__device__ __forceinline__ unsigned int pack2(float a, float b){
    return (unsigned int)f2b(a) | ((unsigned int)f2b(b) << 16);
}
__device__ __forceinline__ void split_bf(float v, unsigned short* hi, unsigned short* lo){
    __hip_bfloat16 h = __float2bfloat16(v);
    float hf = __bfloat162float(h);
    __hip_bfloat16 l = __float2bfloat16(v - hf);
    *hi = *reinterpret_cast<unsigned short*>(&h);
    *lo = *reinterpret_cast<unsigned short*>(&l);
}
__device__ __forceinline__ float sigmoid_safe(float x){
    x = fminf(fmaxf(x, -30.f), 30.f);
    return 1.f / (1.f + __expf(-x));
}

// fp32 VALU 16x128 @ 128x128 + bias (prep role)
__device__ __forceinline__ void mm16f(const float* __restrict__ shX,
                                      const float* __restrict__ W,
                                      const float* __restrict__ bias,
                                      int t, float acc[8])
{
    const int c = t & 15, jg = t >> 4;
    const float4 b0 = *reinterpret_cast<const float4*>(bias + jg*8);
    const float4 b1 = *reinterpret_cast<const float4*>(bias + jg*8 + 4);
    acc[0]=b0.x; acc[1]=b0.y; acc[2]=b0.z; acc[3]=b0.w;
    acc[4]=b1.x; acc[5]=b1.y; acc[6]=b1.z; acc[7]=b1.w;
    const float* Wp = W + jg*8;
    const float* xrow = shX + c*LSTR;
    #pragma unroll 4
    for (int k = 0; k < 128; ++k){
        const float xv = xrow[k];
        const float4 w0 = *reinterpret_cast<const float4*>(Wp + k*128);
        const float4 w1 = *reinterpret_cast<const float4*>(Wp + k*128 + 4);
        acc[0] = fmaf(xv, w0.x, acc[0]); acc[1] = fmaf(xv, w0.y, acc[1]);
        acc[2] = fmaf(xv, w0.z, acc[2]); acc[3] = fmaf(xv, w0.w, acc[3]);
        acc[4] = fmaf(xv, w1.x, acc[4]); acc[5] = fmaf(xv, w1.y, acc[5]);
        acc[6] = fmaf(xv, w1.z, acc[6]); acc[7] = fmaf(xv, w1.w, acc[7]);
    }
}

// ---------- prep0: MW2 = kW.qW^T, mb = qW.kb, kq = kW.qb, s0 = qb.kb ----------
__global__ __launch_bounds__(256) void k_prep0(
    const float* __restrict__ qW, const float* __restrict__ qb,
    const float* __restrict__ kW, const float* __restrict__ kb,
    unsigned short* __restrict__ ws)
{
    float* MW = (float*)(ws + MWF);
    float* mb = (float*)(ws + MBF);
    float* kq = (float*)(ws + KQF);
    float* s0 = (float*)(ws + S0F);
    const int gid = blockIdx.x*256 + threadIdx.x;   // grid 64 -> 16384
    const int e = gid >> 7, f = gid & 127;
    float acc = 0.f;
    for (int d = 0; d < 128; ++d)
        acc = fmaf(kW[e*128+d], qW[f*128+d], acc);
    MW[e*128+f] = acc;   // MW2[e][f]
    if (blockIdx.x == 0){
        const int t = threadIdx.x;
        if (t < 128){
            float a1 = 0.f, a2 = 0.f;
            for (int d = 0; d < 128; ++d){
                a1 = fmaf(qW[t*128+d], kb[d], a1);
                a2 = fmaf(kW[t*128+d], qb[d], a2);
            }
            mb[t] = a1; kq[t] = a2;
        } else if (t == 128){
            float a = 0.f;
            for (int d = 0; d < 128; ++d) a = fmaf(qb[d], kb[d], a);
            s0[0] = a;
        }
    }
}

// ---------- prep1: [0,512) M-GEMM+qbk | [512,704) WT split | [704,4800) XT ----------
__global__ __launch_bounds__(256) void k_prep1(
    const float* __restrict__ x,
    const float* __restrict__ hW, const float* __restrict__ gW,
    const float* __restrict__ s1W, unsigned short* __restrict__ ws)
{
    const int bid = blockIdx.x, t = threadIdx.x;
    if (bid < 512){
        __shared__ float shX[C_*LSTR];
        __shared__ float red[4];
        const float* MW = (const float*)(ws + MWF);
        const float* mb = (const float*)(ws + MBF);
        const float* kq = (const float*)(ws + KQF);
        const float* s0 = (const float*)(ws + S0F);
        float* qbk = (float*)(ws + QBK);
        const long base = (long)bid * CD;
        const float* xp = x + base;
        float part;
        {
            const int pos = 8*t, cc0 = pos >> 7, d0 = pos & 127;
            const float4 v0 = *reinterpret_cast<const float4*>(xp + pos);
            const float4 v1 = *reinterpret_cast<const float4*>(xp + pos + 4);
            float* dst = &shX[cc0*LSTR + d0];
            *reinterpret_cast<float4*>(dst)     = v0;
            *reinterpret_cast<float4*>(dst + 4) = v1;
            part = v0.x*kq[d0]   + v0.y*kq[d0+1] + v0.z*kq[d0+2] + v0.w*kq[d0+3]
                 + v1.x*kq[d0+4] + v1.y*kq[d0+5] + v1.z*kq[d0+6] + v1.w*kq[d0+7];
        }
        #pragma unroll
        for (int s = 1; s < 64; s <<= 1) part += __shfl_xor(part, s);
        if ((t & 63) == 0) red[t >> 6] = part;
        __syncthreads();
        if (t == 0) qbk[bid] = red[0]+red[1]+red[2]+red[3] + 16.f*s0[0];
        float acc[8];
        mm16f(shX, MW, mb, t, acc);
        const int c = t & 15, jg = t >> 4;
        const long o = base + c*128 + jg*8;
        #pragma unroll
        for (int jj = 0; jj < 8; ++jj) ws[MMAT + o + jj] = f2b(acc[jj]);
    } else if (bid < 704){
        const int gid = (bid-512)*256 + t;    // < 49152
        const int mat = gid >> 14, rem = gid & 16383, n = rem >> 7, k = rem & 127;
        const float* W = (mat==0) ? hW : (mat==1) ? gW : s1W;
        split_bf(W[k*128 + n], ws + WTHI + gid, ws + WTLO + gid);
    } else {
        const int gid = (bid-704)*256 + t;    // < 1048576
        const int b = gid >> 17, rem = gid & 131071, r = rem >> 11, cd = rem & 2047;
        ws[XTO + (b*2048 + cd)*64 + r] = f2b(x[gid]);
    }
}

// ---------- W-GEMM (8 waves): wave w owns n-tile w; M=128 (8 m-tiles = 8 pairs) ----------
__device__ __forceinline__ void gemm_W8(const unsigned short* sA,
        const unsigned short* __restrict__ WT_hi, const unsigned short* __restrict__ WT_lo,
        const float* __restrict__ bias, int w, int l15, int quad, float4v acc[8])
{
    const float bv = bias[w*16 + l15];
    #pragma unroll
    for (int mt = 0; mt < 8; ++mt){ float4v d = {bv,bv,bv,bv}; acc[mt] = d; }
    #pragma unroll
    for (int ks = 0; ks < 4; ++ks){
        const int ko = ks*32 + quad*8;
        const int bd = (w*16 + l15)*128 + ko;
        const short8 bh = *reinterpret_cast<const short8*>(WT_hi + bd);
        const short8 bl = *reinterpret_cast<const short8*>(WT_lo + bd);
        #pragma unroll
        for (int mt = 0; mt < 8; ++mt){
            const short8 a = *reinterpret_cast<const short8*>(sA + (mt*16 + l15)*XSTR + mt*8 + ko);
            float4v d = acc[mt];
            d = __builtin_amdgcn_mfma_f32_16x16x32_bf16(a, bh, d, 0,0,0);
            d = __builtin_amdgcn_mfma_f32_16x16x32_bf16(a, bl, d, 0,0,0);
            acc[mt] = d;
        }
    }
}

// ---------- main fused kernel: 512 threads, PG=8 pairs ----------
__global__ __launch_bounds__(512, 4) void k_main(
    const float* __restrict__ x, const float* __restrict__ seq_mask,
    const int* __restrict__ row, const int* __restrict__ col,
    const float* __restrict__ hb, const float* __restrict__ gb,
    const float* __restrict__ s1b, const float* __restrict__ s2W,
    const float* __restrict__ s2b,
    const unsigned short* __restrict__ ws, float* __restrict__ out)
{
    __shared__ __align__(16) unsigned short sX[128*XSTR + 64];  // diff -> x state (skewed tiles)
    __shared__ __align__(16) unsigned short sU[128*XSTR + 64];  // xj -> XG
    __shared__ __align__(16) unsigned short sAl[16*72];
    __shared__ float sLog[1024];    // [kh][pair][r]
    __shared__ float sS[128];
    __shared__ int srp[PG], scp[PG];

    const int t = threadIdx.x;
    const int w = t >> 6, lane = t & 63, l15 = lane & 15, quad = lane >> 4;
    const int p0 = blockIdx.x * PG, b = blockIdx.y;
    const float* xb = x + (size_t)b * R_ * CD;

    if (t < PG){ srp[t] = row[p0+t]; scp[t] = col[p0+t]; }
    for (int i = t; i < 16*72; i += 512) sAl[i] = 0;
    if (t < 128) sS[t] = 0.f;
    __syncthreads();

    // ---- stage diff -> sX, xj -> sU (bf16, pair-skewed tiles) ----
    #pragma unroll
    for (int i = 0; i < 8; ++i){
        const int f4 = t + 512*i;          // 0..4095
        const int flat = f4*4;             // 0..16383
        const int p = flat >> 11, cd = flat & 2047;
        const int ridx = srp[p], cidx = scp[p];
        const float4 a  = *reinterpret_cast<const float4*>(xb + (size_t)ridx*CD + cd);
        const float4 bb = *reinterpret_cast<const float4*>(xb + (size_t)cidx*CD + cd);
        const int ad = (p*16 + (cd>>7))*XSTR + p*8 + (cd & 127);
        uint2 dv, jv;
        dv.x = pack2(a.x-bb.x, a.y-bb.y); dv.y = pack2(a.z-bb.z, a.w-bb.w);
        jv.x = pack2(bb.x, bb.y);         jv.y = pack2(bb.z, bb.w);
        *reinterpret_cast<uint2*>(sX + ad) = dv;
        *reinterpret_cast<uint2*>(sU + ad) = jv;
    }
    __syncthreads();

    float4v acc[8];

    // ---- h-GEMM + gate: x = xj + z*diff (overwrite sX) ----
    gemm_W8(sX, ws+WTHI, ws+WTLO, hb, w, l15, quad, acc);
    __syncthreads();   // all MFMA reads of diff complete before overwrite
    {
        const int colg = w*16 + l15;
        #pragma unroll
        for (int mt = 0; mt < 8; ++mt)
        #pragma unroll
        for (int e = 0; e < 4; ++e){
            const int c = quad*4 + e;
            const int ad = (mt*16 + c)*XSTR + mt*8 + colg;
            const float z = sigmoid_safe(acc[mt][e]);
            sX[ad] = f2b(b2f(sU[ad]) + z * b2f(sX[ad]));
        }
    }
    __syncthreads();

    // ---- alpha GEMM: logits[p][r] = x . M[b,r]  (K=2048 split over kh) ----
    {
        const int rt = w & 3, kh = w >> 2;
        const int r = rt*16 + l15;
        const unsigned short* Mr = ws + MMAT + ((size_t)b*64 + r)*2048 + kh*1024;
        const int pr = l15 & 7;
        float4v d = {0.f,0.f,0.f,0.f};
        #pragma unroll 8
        for (int ks = 0; ks < 32; ++ks){
            const int k = kh*1024 + ks*32 + quad*8;
            const short8 ah = *reinterpret_cast<const short8*>(
                sX + (pr*16 + (k>>7))*XSTR + pr*8 + (k & 127));
            const short8 bh = *reinterpret_cast<const short8*>(Mr + ks*32 + quad*8);
            d = __builtin_amdgcn_mfma_f32_16x16x32_bf16(ah, bh, d, 0,0,0);
        }
        #pragma unroll
        for (int e = 0; e < 4; ++e){
            const int pp = quad*4 + e;
            if (pp < 8) sLog[kh*512 + pp*64 + r] = d[e];
        }
    }
    __syncthreads();

    // ---- masked softmax (threads 0..127: 16 lanes per pair) ----
    if (t < 128){
        const int pp = t >> 4, l = t & 15;
        const int ri = srp[pp], ci = scp[pp];
        const float* qbk = (const float*)(ws + QBK);
        float v[4]; float m = NEG_BIG;
        #pragma unroll
        for (int k = 0; k < 4; ++k){
            const int r = l + 16*k;
            float lv = (sLog[pp*64 + r] + sLog[512 + pp*64 + r] + qbk[b*64 + r]) * SCALE;
            if (r == ri || r == ci) lv = NEG_BIG;
            v[k] = lv; m = fmaxf(m, lv);
        }
        #pragma unroll
        for (int s = 1; s < 16; s <<= 1) m = fmaxf(m, __shfl_xor(m, s));
        float e4[4]; float sum = 0.f;
        #pragma unroll
        for (int k = 0; k < 4; ++k){
            const int r = l + 16*k;
            const bool masked = (r == ri || r == ci);
            const float e = masked ? 0.f : __expf(fmaxf(v[k]-m, -80.f));
            e4[k] = e; sum += e;
        }
        #pragma unroll
        for (int s = 1; s < 16; s <<= 1) sum += __shfl_xor(sum, s);
        const float inv = 1.f / sum;
        #pragma unroll
        for (int k = 0; k < 4; ++k) sAl[pp*72 + l + 16*k] = f2b(e4[k]*inv);
    }
    __syncthreads();

    // ---- x_glob GEMM: XG[p][cd] = alpha @ X (K=64); wave w -> cd in [256w, 256w+256) ----
    {
        const unsigned short* XTb = ws + XTO + (size_t)b * 2048 * 64;
        const short8 Ah0 = *reinterpret_cast<const short8*>(sAl + l15*72 + quad*8);
        const short8 Ah1 = *reinterpret_cast<const short8*>(sAl + l15*72 + 32 + quad*8);
        #pragma unroll 4
        for (int j = 0; j < 16; ++j){
            const int cd = (w*16 + j)*16 + l15;
            const short8 b0 = *reinterpret_cast<const short8*>(XTb + (size_t)cd*64 + quad*8);
            const short8 b1 = *reinterpret_cast<const short8*>(XTb + (size_t)cd*64 + 32 + quad*8);
            float4v d = {0.f,0.f,0.f,0.f};
            d = __builtin_amdgcn_mfma_f32_16x16x32_bf16(Ah0, b0, d, 0,0,0);
            d = __builtin_amdgcn_mfma_f32_16x16x32_bf16(Ah1, b1, d, 0,0,0);
            if (quad < 2){
                #pragma unroll
                for (int e = 0; e < 4; ++e){
                    const int pp = quad*4 + e;
                    sU[(pp*16 + (cd>>7))*XSTR + pp*8 + (cd&127)] = f2b(d[e]);
                }
            }
        }
    }
    __syncthreads();

    // ---- g-GEMM + gate: x = (1-w)*x + w*xg (overwrite sX) ----
    gemm_W8(sU, ws+WTHI+16384, ws+WTLO+16384, gb, w, l15, quad, acc);
    {
        const int colg = w*16 + l15;
        #pragma unroll
        for (int mt = 0; mt < 8; ++mt)
        #pragma unroll
        for (int e = 0; e < 4; ++e){
            const int ad = (mt*16 + quad*4 + e)*XSTR + mt*8 + colg;
            const float wv = sigmoid_safe(acc[mt][e]);
            sX[ad] = f2b((1.f - wv)*b2f(sX[ad]) + wv*b2f(sU[ad]));
        }
    }
    __syncthreads();

    // ---- s1-GEMM + gelu + s2 reduce ----
    gemm_W8(sX, ws+WTHI+32768, ws+WTLO+32768, s1b, w, l15, quad, acc);
    {
        const int colg = w*16 + l15;
        const float s2v = s2W[colg];
        #pragma unroll
        for (int mt = 0; mt < 8; ++mt)
        #pragma unroll
        for (int e = 0; e < 4; ++e){
            const int rowi = mt*16 + quad*4 + e;
            const float tv = acc[mt][e];
            const float gl = 0.5f * tv * (1.f + erff(tv * 0.70710678118654752f));
            float part = gl * s2v;
            #pragma unroll
            for (int s = 1; s < 16; s <<= 1) part += __shfl_xor(part, s);
            if (l15 == 0) atomicAdd(&sS[rowi], part);
        }
    }
    __syncthreads();

    if (t < PG){
        const float s2bv = s2b[0];
        float o = 0.f;
        #pragma unroll
        for (int c = 0; c < 16; ++c)
            o += (sS[t*16 + c] + s2bv) * seq_mask[b*C_ + c];
        out[(size_t)b*NPAIR + p0 + t] = o;
    }
}

extern "C" void kernel_launch(void* const* d_in, const int* in_sizes, int n_in,
                              void* d_out, int out_size, void* d_ws, size_t ws_size,
                              hipStream_t stream)
{
    const float* x    = (const float*)d_in[0];
    const float* mask = (const float*)d_in[1];
    const int*   row  = (const int*)d_in[2];
    const int*   col  = (const int*)d_in[3];
    const float* hW  = (const float*)d_in[4];  const float* hb  = (const float*)d_in[5];
    const float* gW  = (const float*)d_in[6];  const float* gb  = (const float*)d_in[7];
    const float* qW  = (const float*)d_in[8];  const float* qb  = (const float*)d_in[9];
    const float* kW  = (const float*)d_in[10]; const float* kb  = (const float*)d_in[11];
    const float* s1W = (const float*)d_in[12]; const float* s1b = (const float*)d_in[13];
    const float* s2W = (const float*)d_in[14]; const float* s2b = (const float*)d_in[15];

    unsigned short* ws = (unsigned short*)d_ws;   // 4.46 MB used

    k_prep0<<<64, 256, 0, stream>>>(qW, qb, kW, kb, ws);
    k_prep1<<<4800, 256, 0, stream>>>(x, hW, gW, s1W, ws);
    k_main<<<dim3(NPAIR/PG, B_), 512, 0, stream>>>(x, mask, row, col,
                                                   hb, gb, s1b, s2W, s2b,
                                                   ws, (float*)d_out);
}